// Round 1
// baseline (18.005 us; speedup 1.0000x reference)
//
#include <hip/hip_runtime.h>
#include <hip/hip_bf16.h>

// TrueQLACI_Quantum: exact closed form.
//
// The quantum subcircuit (CNOT fan-in, RZ(theta_j), CNOT fan-out, repeated
// over 15 keys) is diagonal in the computational basis. Wire 8 starts in |0>;
// the conditional swaps + diagonal phase compose to a pure per-component
// phase, so the |1> amplitude stays exactly 0 and each of the 16 branch
// amplitudes keeps modulus 0.25. Hence <Z_8> = 16 * 0.0625 = 1.0 for EVERY
// sample, independent of tokens/q/k.
//
// reference(...) = 1.0 @ W_out.T + b_out  ->  out[b][i] = W_out[i] + b_out[i]
// broadcast over B = 131072 rows. The kernel is a 16 MiB constant-row store.

__global__ __launch_bounds__(256) void qlaci_broadcast(
        const float* __restrict__ W_out,   // [32] (flat of [32,1])
        const float* __restrict__ b_out,   // [32]
        float4* __restrict__ out,          // [B*32/4] float4
        int n4) {
    // One row = 32 floats = 8 float4 groups; precompute them per block.
    __shared__ float4 vals[8];
    if (threadIdx.x < 8) {
        const int c = threadIdx.x * 4;
        vals[threadIdx.x] = make_float4(W_out[c + 0] + b_out[c + 0],
                                        W_out[c + 1] + b_out[c + 1],
                                        W_out[c + 2] + b_out[c + 2],
                                        W_out[c + 3] + b_out[c + 3]);
    }
    __syncthreads();

    for (int i = blockIdx.x * blockDim.x + threadIdx.x; i < n4;
         i += gridDim.x * blockDim.x) {
        out[i] = vals[i & 7];
    }
}

extern "C" void kernel_launch(void* const* d_in, const int* in_sizes, int n_in,
                              void* d_out, int out_size, void* d_ws, size_t ws_size,
                              hipStream_t stream) {
    // setup_inputs order: tokens, W_emb, b_emb, W_q, b_q, W_k, b_k, W_out, b_out
    const float* W_out = (const float*)d_in[7];  // 32 elements
    const float* b_out = (const float*)d_in[8];  // 32 elements
    float4* out = (float4*)d_out;

    const int n4 = out_size / 4;                 // 4194304 / 4 = 1048576
    const int block = 256;
    int grid = (n4 + block - 1) / block;
    if (grid > 2048) grid = 2048;                // grid-stride the rest

    qlaci_broadcast<<<grid, block, 0, stream>>>(W_out, b_out, out, n4);
}

// Round 2
// 11.226 us; speedup vs baseline: 1.6039x; 1.6039x over previous
//
#include <hip/hip_runtime.h>
#include <hip/hip_bf16.h>

// TrueQLACI_Quantum: exact closed form.
//
// The quantum subcircuit (CNOT fan-in, RZ(theta_j), CNOT fan-out, repeated
// over 15 keys) is diagonal in the computational basis. Wire 8 starts in |0>;
// the conditional swaps + diagonal phase compose to a pure per-component
// phase, so the |1> amplitude stays exactly 0 and each of the 16 branch
// amplitudes keeps modulus 0.25. Hence <Z_8> = 16 * 0.0625 = 1.0 for EVERY
// sample, independent of tokens/q/k.
//
// reference(...) = 1.0 @ W_out.T + b_out  ->  out[b][i] = W_out[i] + b_out[i]
// broadcast over B = 131072 rows: a 16 MiB constant-row store.
//
// This version: one float4 store per thread, no LDS, no barrier, no loop.
// W_out/b_out are 256 B total -> L1-broadcast loads; critical path is
// load -> add -> store only.

__global__ __launch_bounds__(256) void qlaci_broadcast(
        const float4* __restrict__ W_out,  // [8] float4 (32 floats)
        const float4* __restrict__ b_out,  // [8] float4
        float4* __restrict__ out,          // [B*32/4] float4
        int n4) {
    const int i = blockIdx.x * blockDim.x + threadIdx.x;
    if (i >= n4) return;
    const int c = i & 7;                   // column group within the 32-wide row
    const float4 w = W_out[c];
    const float4 b = b_out[c];
    out[i] = make_float4(w.x + b.x, w.y + b.y, w.z + b.z, w.w + b.w);
}

extern "C" void kernel_launch(void* const* d_in, const int* in_sizes, int n_in,
                              void* d_out, int out_size, void* d_ws, size_t ws_size,
                              hipStream_t stream) {
    // setup_inputs order: tokens, W_emb, b_emb, W_q, b_q, W_k, b_k, W_out, b_out
    const float4* W_out = (const float4*)d_in[7];  // 32 floats
    const float4* b_out = (const float4*)d_in[8];  // 32 floats
    float4* out = (float4*)d_out;

    const int n4 = out_size / 4;                   // 4194304 / 4 = 1048576
    const int block = 256;
    const int grid = (n4 + block - 1) / block;     // 4096: one store per thread

    qlaci_broadcast<<<grid, block, 0, stream>>>(W_out, b_out, out, n4);
}